// Round 4
// baseline (253.400 us; speedup 1.0000x reference)
//
#include <hip/hip_runtime.h>
#include <hip/hip_fp16.h>

#define NDIM 8192
#define KDIM 8192
#define NT 256          // N / 32 hash tiles
#define MOD2 4193281    // HASH_SIZE - 32*32 + 1
#define PRIME 2038074743LL

#define BM 128
#define BN 128
#define BK 32
#define KITER 128       // (KDIM/2)/BK, split-K = 2
#define ASTRIDE 40      // halves per A row (32 + 8 pad; b128-aligned, phase-balanced)
#define BSLAB 1032      // halves per k-octet slab (128*8 + 8 pad; phase-balanced)

typedef _Float16 half8 __attribute__((ext_vector_type(8)));
typedef float floatx4 __attribute__((ext_vector_type(4)));

// ---------------- fused prepass: cvt fp32->f16, out=bias, ROBE-Z starts ----------------
__global__ __launch_bounds__(256) void prep_kernel(const float* __restrict__ x,
                                                   const float* __restrict__ hw,
                                                   const float* __restrict__ bias,
                                                   const int* __restrict__ rn,
                                                   __half* __restrict__ xh,
                                                   __half* __restrict__ hh,
                                                   int* __restrict__ starts,
                                                   float* __restrict__ out) {
    int b = blockIdx.x;
    int tid = threadIdx.x;
    if (b < 8192) {                       // cvt: 2M threads x 4 floats
        int i = b * 256 + tid;
        const float4* s; __half2* d; int j;
        if (i < (1 << 20)) { s = (const float4*)x;  d = (__half2*)xh; j = i; }
        else               { s = (const float4*)hw; d = (__half2*)hh; j = i - (1 << 20); }
        float4 v = s[j];
        d[j * 2]     = __floats2half2_rn(v.x, v.y);
        d[j * 2 + 1] = __floats2half2_rn(v.z, v.w);
    } else if (b < 8192 + 4096) {         // init: out = bias (atomic targets)
        int i = (b - 8192) * 256 + tid;
        float4 bv = *(const float4*)(bias + ((i & 2047) << 2));
        ((float4*)out)[i] = bv;
    } else {                              // starts: 64K hash tile offsets
        int t = (b - 12288) * 256 + tid;
        bool is64 = (rn[1] == 0 && rn[3] == 0);   // int64 input: words 1,3 are hi-halves
        long long R1 = is64 ? rn[2] : rn[1];
        long long R2 = is64 ? rn[4] : rn[2];
        long long R3 = is64 ? rn[6] : rn[3];
        long long k_id = t >> 8, n_id = t & 255;
        long long v = (k_id * R3 + n_id * R2 + R1) % PRIME;
        starts[t] = (int)(v % MOD2);
    }
}

// ---------------- main GEMM: split-K=2, 128x128 block, 4 waves, dist-2 prefetch ----------------
// Same proven sync structure (__syncthreads, dist-2 reg prefetch, dbuf LDS) as the
// 126us kernel; tile shrunk 256x128->128x128 so 4 blocks/CU fit (39KB LDS vs 58.5KB).
__global__ __launch_bounds__(256, 4) void gemm_kernel(
    const __half* __restrict__ xh, const __half* __restrict__ hh,
    const int* __restrict__ starts, float* __restrict__ out) {
    __shared__ __align__(16) __half As[2][BM * ASTRIDE];   // [m][k] padded   : 20480 B
    __shared__ __align__(16) __half Bs[2][4 * BSLAB];      // [k-octet][n][8] : 16512 B
    __shared__ int Ss[KITER * 4];                          // starts table    :  2048 B

    const int tid = threadIdx.x;
    const int lane = tid & 63;
    const int wave = tid >> 6;       // 0..3
    const int wm = wave >> 1;        // 0..1 : 64-row strip
    const int wn = wave & 1;         // 0..1 : 64-col strip
    const int quad = lane >> 4;
    const int l16 = lane & 15;

    const int i = blockIdx.x;        // 512 blocks = 2 ks x 4 m x 64 n
    const int ks = i & 1;
    const int m_blk = (i >> 1) & 3;
    const int n_blk = i >> 3;        // 0..63
    const int gm0 = m_blk * BM;
    const int gn0 = n_blk * BN;
    const int kt0 = ks * KITER;
    const int n_id0 = n_blk * 4;     // 4 hash tiles per block

    for (int s = tid; s < KITER * 4; s += 256) {
        int kp = s >> 2, tile = s & 3;
        Ss[s] = starts[(kt0 + kp) * NT + n_id0 + tile];
    }

    // A staging: thread covers rows (tid>>2) and (tid>>2)+64, 16B chunk tid&3
    const int a_row = tid >> 2;               // 0..63
    const int a_ch = tid & 3;
    const __half* aptr = xh + (size_t)(gm0 + a_row) * KDIM + kt0 * 32 + a_ch * 8;
    const unsigned a_woff = a_row * ASTRIDE + a_ch * 8;

    // B staging: 64 threads per 32x32 hash tile; thread covers 2 n x 8 k
    const int b_tile = tid >> 6;              // 0..3
    const int t6 = tid & 63;
    const int b_np = t6 & 15;                 // n-pair
    const int b_kg = t6 >> 4;                 // 0..3 : low 4-k group (also covers b_kg+4)
    const int b_oct = b_kg >> 1;
    const unsigned b_woff = b_oct * BSLAB + (b_tile * 32 + 2 * b_np) * 8 + (b_kg & 1) * 4;

    // two STATIC register sets (no arrays -> no dynamic indexing -> no spill)
    uint4 paA0, paA1, paB0, paB1;
    unsigned pbA0, pbA1, pbA2, pbA3, pbA4, pbA5, pbA6, pbA7;
    unsigned pbB0, pbB1, pbB2, pbB3, pbB4, pbB5, pbB6, pbB7;

#define LOADT(P0, P1, Q0, Q1, Q2, Q3, Q4, Q5, Q6, Q7, kp_) do {                \
        P0 = *(const uint4*)(aptr + (kp_) * 32);                               \
        P1 = *(const uint4*)(aptr + (size_t)64 * KDIM + (kp_) * 32);           \
        int st = Ss[(kp_) * 4 + b_tile];                                       \
        const __half* src = hh + st + b_kg * 128 + b_np * 2;                   \
        Q0 = *(const unsigned*)(src);                                          \
        Q1 = *(const unsigned*)(src + 32);                                     \
        Q2 = *(const unsigned*)(src + 64);                                     \
        Q3 = *(const unsigned*)(src + 96);                                     \
        Q4 = *(const unsigned*)(src + 512);                                    \
        Q5 = *(const unsigned*)(src + 544);                                    \
        Q6 = *(const unsigned*)(src + 576);                                    \
        Q7 = *(const unsigned*)(src + 608);                                    \
    } while (0)

#define STORET(P0, P1, Q0, Q1, Q2, Q3, Q4, Q5, Q6, Q7, buf_) do {              \
        *(uint4*)&As[buf_][a_woff] = P0;                                       \
        *(uint4*)&As[buf_][(a_woff) + 64 * ASTRIDE] = P1;                      \
        unsigned lo0 = (Q0 & 0xffffu) | (Q1 << 16);                            \
        unsigned lo1 = (Q2 & 0xffffu) | (Q3 << 16);                            \
        unsigned hi0 = (Q0 >> 16) | (Q1 & 0xffff0000u);                        \
        unsigned hi1 = (Q2 >> 16) | (Q3 & 0xffff0000u);                        \
        uint2 e0 = {lo0, lo1}, o0 = {hi0, hi1};                                \
        *(uint2*)&Bs[buf_][b_woff] = e0;                                       \
        *(uint2*)&Bs[buf_][b_woff + 8] = o0;                                   \
        unsigned lo2 = (Q4 & 0xffffu) | (Q5 << 16);                            \
        unsigned lo3 = (Q6 & 0xffffu) | (Q7 << 16);                            \
        unsigned hi2 = (Q4 >> 16) | (Q5 & 0xffff0000u);                        \
        unsigned hi3 = (Q6 >> 16) | (Q7 & 0xffff0000u);                        \
        uint2 e1 = {lo2, lo3}, o1 = {hi2, hi3};                                \
        *(uint2*)&Bs[buf_][b_woff + 2 * BSLAB] = e1;                           \
        *(uint2*)&Bs[buf_][b_woff + 2 * BSLAB + 8] = o1;                       \
    } while (0)

    floatx4 acc[4][4];
#pragma unroll
    for (int r = 0; r < 4; r++)
#pragma unroll
        for (int c = 0; c < 4; c++)
            acc[r][c] = (floatx4){0.f, 0.f, 0.f, 0.f};

#define FRAGS_MFMA(buf_) do {                                                  \
        half8 af[4], bf[4];                                                    \
        _Pragma("unroll")                                                      \
        for (int r = 0; r < 4; r++)                                            \
            af[r] = *(const half8*)&As[buf_][(wm * 64 + r * 16 + l16) * ASTRIDE + quad * 8]; \
        _Pragma("unroll")                                                      \
        for (int c = 0; c < 4; c++)                                            \
            bf[c] = *(const half8*)&Bs[buf_][quad * BSLAB + (wn * 64 + c * 16 + l16) * 8];   \
        _Pragma("unroll")                                                      \
        for (int r = 0; r < 4; r++)                                            \
            _Pragma("unroll")                                                  \
            for (int c = 0; c < 4; c++)                                        \
                acc[r][c] = __builtin_amdgcn_mfma_f32_16x16x32_f16(af[r], bf[c], acc[r][c], 0, 0, 0); \
    } while (0)

    __syncthreads();                  // Ss visible
    LOADT(paA0, paA1, pbA0, pbA1, pbA2, pbA3, pbA4, pbA5, pbA6, pbA7, 0);
    LOADT(paB0, paB1, pbB0, pbB1, pbB2, pbB3, pbB4, pbB5, pbB6, pbB7, 1);
    STORET(paA0, paA1, pbA0, pbA1, pbA2, pbA3, pbA4, pbA5, pbA6, pbA7, 0);
    __syncthreads();

    for (int kp = 0; kp < KITER; kp += 2) {
        // even half-iter: compute tile kp from buf0; set A free
        if (kp + 2 < KITER)
            LOADT(paA0, paA1, pbA0, pbA1, pbA2, pbA3, pbA4, pbA5, pbA6, pbA7, kp + 2);
        FRAGS_MFMA(0);
        STORET(paB0, paB1, pbB0, pbB1, pbB2, pbB3, pbB4, pbB5, pbB6, pbB7, 1);
        __syncthreads();

        // odd half-iter: compute tile kp+1 from buf1; set B free
        if (kp + 3 < KITER)
            LOADT(paB0, paB1, pbB0, pbB1, pbB2, pbB3, pbB4, pbB5, pbB6, pbB7, kp + 3);
        FRAGS_MFMA(1);
        if (kp + 2 < KITER)
            STORET(paA0, paA1, pbA0, pbA1, pbA2, pbA3, pbA4, pbA5, pbA6, pbA7, 0);
        __syncthreads();
    }

    // ---- epilogue: atomic accumulate (C/D layout col=lane&15, row=quad*4+reg) ----
#pragma unroll
    for (int c = 0; c < 4; c++) {
        int col = gn0 + wn * 64 + c * 16 + l16;
#pragma unroll
        for (int r = 0; r < 4; r++) {
            int row0 = gm0 + wm * 64 + r * 16 + quad * 4;
#pragma unroll
            for (int e = 0; e < 4; e++)
                atomicAdd(&out[(size_t)(row0 + e) * NDIM + col], acc[r][c][e]);
        }
    }
#undef LOADT
#undef STORET
#undef FRAGS_MFMA
}

extern "C" void kernel_launch(void* const* d_in, const int* in_sizes, int n_in,
                              void* d_out, int out_size, void* d_ws, size_t ws_size,
                              hipStream_t stream) {
    const float* x = (const float*)d_in[0];
    const float* hw = (const float*)d_in[1];
    const float* bias = (const float*)d_in[2];
    const int* rn = (const int*)d_in[3];
    float* out = (float*)d_out;

    char* ws = (char*)d_ws;
    __half* xh = (__half*)ws;                          // 8 MB : x as f16
    __half* hh = (__half*)(ws + (8u << 20));           // 8 MB : hashed_weight as f16
    int* starts = (int*)(ws + (16u << 20));            // 256 KB : tile start table

    hipLaunchKernelGGL(prep_kernel, dim3(12544), dim3(256), 0, stream,
                       x, hw, bias, rn, xh, hh, starts, out);
    hipLaunchKernelGGL(gemm_kernel, dim3(512), dim3(256), 0, stream, xh, hh, starts, out);
}

// Round 5
// 245.060 us; speedup vs baseline: 1.0340x; 1.0340x over previous
//
#include <hip/hip_runtime.h>
#include <hip/hip_fp16.h>

#define NDIM 8192
#define KDIM 8192
#define NT 256          // N / 32 hash tiles
#define MOD2 4193281    // HASH_SIZE - 32*32 + 1
#define PRIME 2038074743LL

#define BM 128
#define BN 128
#define BK 32
#define KITER 64        // (KDIM/4)/BK, split-K = 4
#define ASTRIDE 40      // halves per A row (32 + 8 pad; b128-aligned, phase-balanced)
#define BSLAB 1032      // halves per k-octet slab (128*8 + 8 pad; phase-balanced)

typedef _Float16 half8 __attribute__((ext_vector_type(8)));
typedef float floatx4 __attribute__((ext_vector_type(4)));

// ---------------- fused prepass: cvt fp32->f16, out=bias, ROBE-Z starts ----------------
__global__ __launch_bounds__(256) void prep_kernel(const float* __restrict__ x,
                                                   const float* __restrict__ hw,
                                                   const float* __restrict__ bias,
                                                   const int* __restrict__ rn,
                                                   __half* __restrict__ xh,
                                                   __half* __restrict__ hh,
                                                   int* __restrict__ starts,
                                                   float* __restrict__ out) {
    int b = blockIdx.x;
    int tid = threadIdx.x;
    if (b < 8192) {                       // cvt: 2M threads x 4 floats
        int i = b * 256 + tid;
        const float4* s; __half2* d; int j;
        if (i < (1 << 20)) { s = (const float4*)x;  d = (__half2*)xh; j = i; }
        else               { s = (const float4*)hw; d = (__half2*)hh; j = i - (1 << 20); }
        float4 v = s[j];
        d[j * 2]     = __floats2half2_rn(v.x, v.y);
        d[j * 2 + 1] = __floats2half2_rn(v.z, v.w);
    } else if (b < 8192 + 4096) {         // init: out = bias (atomic targets)
        int i = (b - 8192) * 256 + tid;
        float4 bv = *(const float4*)(bias + ((i & 2047) << 2));
        ((float4*)out)[i] = bv;
    } else {                              // starts: 64K hash tile offsets
        int t = (b - 12288) * 256 + tid;
        bool is64 = (rn[1] == 0 && rn[3] == 0);   // int64 input: words 1,3 are hi-halves
        long long R1 = is64 ? rn[2] : rn[1];
        long long R2 = is64 ? rn[4] : rn[2];
        long long R3 = is64 ? rn[6] : rn[3];
        long long k_id = t >> 8, n_id = t & 255;
        long long v = (k_id * R3 + n_id * R2 + R1) % PRIME;
        starts[t] = (int)(v % MOD2);
    }
}

// ---------------- main GEMM: split-K=4, 128x128 block, 4 waves, dist-2 prefetch ----------------
// R4 structure verbatim; split-K 2->4 so grid = 1024 blocks -> 4 resident blocks/CU
// (4 x 39.4 KB = 157.7 KB LDS). Same 16 waves/CU as the 126us kernel but in 4
// independently-synced barrier groups instead of 2.
__global__ __launch_bounds__(256, 4) void gemm_kernel(
    const __half* __restrict__ xh, const __half* __restrict__ hh,
    const int* __restrict__ starts, float* __restrict__ out) {
    __shared__ __align__(16) __half As[2][BM * ASTRIDE];   // [m][k] padded   : 20480 B
    __shared__ __align__(16) __half Bs[2][4 * BSLAB];      // [k-octet][n][8] : 16512 B
    __shared__ int Ss[KITER * 4];                          // starts table    :  1024 B

    const int tid = threadIdx.x;
    const int lane = tid & 63;
    const int wave = tid >> 6;       // 0..3
    const int wm = wave >> 1;        // 0..1 : 64-row strip
    const int wn = wave & 1;         // 0..1 : 64-col strip
    const int quad = lane >> 4;
    const int l16 = lane & 15;

    const int i = blockIdx.x;        // 1024 blocks = 4 ks x 4 m x 64 n
    const int ks = i & 3;
    const int m_blk = (i >> 2) & 3;
    const int n_blk = i >> 4;        // 0..63
    const int gm0 = m_blk * BM;
    const int gn0 = n_blk * BN;
    const int kt0 = ks * KITER;
    const int n_id0 = n_blk * 4;     // 4 hash tiles per block

    if (tid < KITER * 4) {
        int kp = tid >> 2, tile = tid & 3;
        Ss[tid] = starts[(kt0 + kp) * NT + n_id0 + tile];
    }

    // A staging: thread covers rows (tid>>2) and (tid>>2)+64, 16B chunk tid&3
    const int a_row = tid >> 2;               // 0..63
    const int a_ch = tid & 3;
    const __half* aptr = xh + (size_t)(gm0 + a_row) * KDIM + kt0 * 32 + a_ch * 8;
    const unsigned a_woff = a_row * ASTRIDE + a_ch * 8;

    // B staging: 64 threads per 32x32 hash tile; thread covers 2 n x 8 k
    const int b_tile = tid >> 6;              // 0..3
    const int t6 = tid & 63;
    const int b_np = t6 & 15;                 // n-pair
    const int b_kg = t6 >> 4;                 // 0..3 : low 4-k group (also covers b_kg+4)
    const int b_oct = b_kg >> 1;
    const unsigned b_woff = b_oct * BSLAB + (b_tile * 32 + 2 * b_np) * 8 + (b_kg & 1) * 4;

    // two STATIC register sets (no arrays -> no dynamic indexing -> no spill)
    uint4 paA0, paA1, paB0, paB1;
    unsigned pbA0, pbA1, pbA2, pbA3, pbA4, pbA5, pbA6, pbA7;
    unsigned pbB0, pbB1, pbB2, pbB3, pbB4, pbB5, pbB6, pbB7;

#define LOADT(P0, P1, Q0, Q1, Q2, Q3, Q4, Q5, Q6, Q7, kp_) do {                \
        P0 = *(const uint4*)(aptr + (kp_) * 32);                               \
        P1 = *(const uint4*)(aptr + (size_t)64 * KDIM + (kp_) * 32);           \
        int st = Ss[(kp_) * 4 + b_tile];                                       \
        const __half* src = hh + st + b_kg * 128 + b_np * 2;                   \
        Q0 = *(const unsigned*)(src);                                          \
        Q1 = *(const unsigned*)(src + 32);                                     \
        Q2 = *(const unsigned*)(src + 64);                                     \
        Q3 = *(const unsigned*)(src + 96);                                     \
        Q4 = *(const unsigned*)(src + 512);                                    \
        Q5 = *(const unsigned*)(src + 544);                                    \
        Q6 = *(const unsigned*)(src + 576);                                    \
        Q7 = *(const unsigned*)(src + 608);                                    \
    } while (0)

#define STORET(P0, P1, Q0, Q1, Q2, Q3, Q4, Q5, Q6, Q7, buf_) do {              \
        *(uint4*)&As[buf_][a_woff] = P0;                                       \
        *(uint4*)&As[buf_][(a_woff) + 64 * ASTRIDE] = P1;                      \
        unsigned lo0 = (Q0 & 0xffffu) | (Q1 << 16);                            \
        unsigned lo1 = (Q2 & 0xffffu) | (Q3 << 16);                            \
        unsigned hi0 = (Q0 >> 16) | (Q1 & 0xffff0000u);                        \
        unsigned hi1 = (Q2 >> 16) | (Q3 & 0xffff0000u);                        \
        uint2 e0 = {lo0, lo1}, o0 = {hi0, hi1};                                \
        *(uint2*)&Bs[buf_][b_woff] = e0;                                       \
        *(uint2*)&Bs[buf_][b_woff + 8] = o0;                                   \
        unsigned lo2 = (Q4 & 0xffffu) | (Q5 << 16);                            \
        unsigned lo3 = (Q6 & 0xffffu) | (Q7 << 16);                            \
        unsigned hi2 = (Q4 >> 16) | (Q5 & 0xffff0000u);                        \
        unsigned hi3 = (Q6 >> 16) | (Q7 & 0xffff0000u);                        \
        uint2 e1 = {lo2, lo3}, o1 = {hi2, hi3};                                \
        *(uint2*)&Bs[buf_][b_woff + 2 * BSLAB] = e1;                           \
        *(uint2*)&Bs[buf_][b_woff + 2 * BSLAB + 8] = o1;                       \
    } while (0)

    floatx4 acc[4][4];
#pragma unroll
    for (int r = 0; r < 4; r++)
#pragma unroll
        for (int c = 0; c < 4; c++)
            acc[r][c] = (floatx4){0.f, 0.f, 0.f, 0.f};

#define FRAGS_MFMA(buf_) do {                                                  \
        half8 af[4], bf[4];                                                    \
        _Pragma("unroll")                                                      \
        for (int r = 0; r < 4; r++)                                            \
            af[r] = *(const half8*)&As[buf_][(wm * 64 + r * 16 + l16) * ASTRIDE + quad * 8]; \
        _Pragma("unroll")                                                      \
        for (int c = 0; c < 4; c++)                                            \
            bf[c] = *(const half8*)&Bs[buf_][quad * BSLAB + (wn * 64 + c * 16 + l16) * 8];   \
        _Pragma("unroll")                                                      \
        for (int r = 0; r < 4; r++)                                            \
            _Pragma("unroll")                                                  \
            for (int c = 0; c < 4; c++)                                        \
                acc[r][c] = __builtin_amdgcn_mfma_f32_16x16x32_f16(af[r], bf[c], acc[r][c], 0, 0, 0); \
    } while (0)

    __syncthreads();                  // Ss visible
    LOADT(paA0, paA1, pbA0, pbA1, pbA2, pbA3, pbA4, pbA5, pbA6, pbA7, 0);
    LOADT(paB0, paB1, pbB0, pbB1, pbB2, pbB3, pbB4, pbB5, pbB6, pbB7, 1);
    STORET(paA0, paA1, pbA0, pbA1, pbA2, pbA3, pbA4, pbA5, pbA6, pbA7, 0);
    __syncthreads();

    for (int kp = 0; kp < KITER; kp += 2) {
        // even half-iter: compute tile kp from buf0; set A free
        if (kp + 2 < KITER)
            LOADT(paA0, paA1, pbA0, pbA1, pbA2, pbA3, pbA4, pbA5, pbA6, pbA7, kp + 2);
        FRAGS_MFMA(0);
        STORET(paB0, paB1, pbB0, pbB1, pbB2, pbB3, pbB4, pbB5, pbB6, pbB7, 1);
        __syncthreads();

        // odd half-iter: compute tile kp+1 from buf1; set B free
        if (kp + 3 < KITER)
            LOADT(paB0, paB1, pbB0, pbB1, pbB2, pbB3, pbB4, pbB5, pbB6, pbB7, kp + 3);
        FRAGS_MFMA(1);
        if (kp + 2 < KITER)
            STORET(paA0, paA1, pbA0, pbA1, pbA2, pbA3, pbA4, pbA5, pbA6, pbA7, 0);
        __syncthreads();
    }

    // ---- epilogue: atomic accumulate (C/D layout col=lane&15, row=quad*4+reg) ----
#pragma unroll
    for (int c = 0; c < 4; c++) {
        int col = gn0 + wn * 64 + c * 16 + l16;
#pragma unroll
        for (int r = 0; r < 4; r++) {
            int row0 = gm0 + wm * 64 + r * 16 + quad * 4;
#pragma unroll
            for (int e = 0; e < 4; e++)
                atomicAdd(&out[(size_t)(row0 + e) * NDIM + col], acc[r][c][e]);
        }
    }
#undef LOADT
#undef STORET
#undef FRAGS_MFMA
}

extern "C" void kernel_launch(void* const* d_in, const int* in_sizes, int n_in,
                              void* d_out, int out_size, void* d_ws, size_t ws_size,
                              hipStream_t stream) {
    const float* x = (const float*)d_in[0];
    const float* hw = (const float*)d_in[1];
    const float* bias = (const float*)d_in[2];
    const int* rn = (const int*)d_in[3];
    float* out = (float*)d_out;

    char* ws = (char*)d_ws;
    __half* xh = (__half*)ws;                          // 8 MB : x as f16
    __half* hh = (__half*)(ws + (8u << 20));           // 8 MB : hashed_weight as f16
    int* starts = (int*)(ws + (16u << 20));            // 256 KB : tile start table

    hipLaunchKernelGGL(prep_kernel, dim3(12544), dim3(256), 0, stream,
                       x, hw, bias, rn, xh, hh, starts, out);
    hipLaunchKernelGGL(gemm_kernel, dim3(1024), dim3(256), 0, stream, xh, hh, starts, out);
}

// Round 6
// 200.172 us; speedup vs baseline: 1.2659x; 1.2242x over previous
//
#include <hip/hip_runtime.h>
#include <hip/hip_fp16.h>

#define NDIM 8192
#define KDIM 8192
#define NT 256          // N / 32 hash tiles
#define MOD2 4193281    // HASH_SIZE - 32*32 + 1
#define PRIME 2038074743LL

#define BM 256
#define BN 128
#define BK 32
#define KITER 64        // (KDIM/4)/BK, split-K = 4
#define ASTRIDE 40      // halves per A row (32 + 8 pad; b128-aligned, phase-balanced)
#define BSLAB 1032      // halves per k-octet slab (128*8 + 8 pad; phase-balanced)

typedef _Float16 half8 __attribute__((ext_vector_type(8)));
typedef float floatx4 __attribute__((ext_vector_type(4)));

// ---------------- fused prepass: cvt fp32->f16, out=bias, ROBE-Z starts ----------------
__global__ __launch_bounds__(256) void prep_kernel(const float* __restrict__ x,
                                                   const float* __restrict__ hw,
                                                   const float* __restrict__ bias,
                                                   const int* __restrict__ rn,
                                                   __half* __restrict__ xh,
                                                   __half* __restrict__ hh,
                                                   int* __restrict__ starts,
                                                   float* __restrict__ out) {
    int b = blockIdx.x;
    int tid = threadIdx.x;
    if (b < 8192) {                       // cvt: 2M threads x 4 floats
        int i = b * 256 + tid;
        const float4* s; __half2* d; int j;
        if (i < (1 << 20)) { s = (const float4*)x;  d = (__half2*)xh; j = i; }
        else               { s = (const float4*)hw; d = (__half2*)hh; j = i - (1 << 20); }
        float4 v = s[j];
        d[j * 2]     = __floats2half2_rn(v.x, v.y);
        d[j * 2 + 1] = __floats2half2_rn(v.z, v.w);
    } else if (b < 8192 + 4096) {         // init: out = bias (atomic targets)
        int i = (b - 8192) * 256 + tid;
        float4 bv = *(const float4*)(bias + ((i & 2047) << 2));
        ((float4*)out)[i] = bv;
    } else {                              // starts: 64K hash tile offsets
        int t = (b - 12288) * 256 + tid;
        bool is64 = (rn[1] == 0 && rn[3] == 0);   // int64 input: words 1,3 are hi-halves
        long long R1 = is64 ? rn[2] : rn[1];
        long long R2 = is64 ? rn[4] : rn[2];
        long long R3 = is64 ? rn[6] : rn[3];
        long long k_id = t >> 8, n_id = t & 255;
        long long v = (k_id * R3 + n_id * R2 + R1) % PRIME;
        starts[t] = (int)(v % MOD2);
    }
}

// ---------------- main GEMM: split-K=4, 256x128 block, manual dist-2 prefetch ----------------
// R1-proven structure (126us). ONE change: B LDS layout XOR-swizzled by (n&8) at
// 16B granularity on BOTH write and read sides -> B ds_write conflicts 4-way->2-way.
__global__ __launch_bounds__(512, 4) void gemm_kernel(
    const __half* __restrict__ xh, const __half* __restrict__ hh,
    const int* __restrict__ starts, float* __restrict__ out) {
    __shared__ __align__(16) __half As[2][BM * ASTRIDE];   // [m][k] padded
    __shared__ __align__(16) __half Bs[2][4 * BSLAB];      // [k-octet][n][8] k-runs, swizzled
    __shared__ int Ss[KITER * 4];                          // per-block starts table

    const int tid = threadIdx.x;
    const int lane = tid & 63;
    const int wave = tid >> 6;       // 0..7
    const int wm = wave >> 1;        // 0..3 : 64-row strip
    const int wn = wave & 1;         // 0..1 : 64-col strip
    const int quad = lane >> 4;
    const int l16 = lane & 15;

    const int i = blockIdx.x;        // 512 blocks
    const int ks = i & 3;
    const int m_blk = (i >> 2) & 1;
    const int n_blk = i >> 3;        // 0..63
    const int gm0 = m_blk * BM;
    const int gn0 = n_blk * BN;
    const int kt0 = ks * KITER;
    const int n_id0 = n_blk * 4;     // 4 hash tiles per block

    if (tid < KITER * 4) {
        int kp = tid >> 2, tile = tid & 3;
        Ss[tid] = starts[(kt0 + kp) * NT + n_id0 + tile];
    }

    // A staging: thread covers rows (tid>>2) and (tid>>2)+128, 16B chunk tid&3
    const int a_row = tid >> 2;               // 0..127
    const int a_ch = tid & 3;
    const __half* aptr = xh + (size_t)(gm0 + a_row) * KDIM + kt0 * 32 + a_ch * 8;
    const unsigned a_woff = a_row * ASTRIDE + a_ch * 8;

    // B staging: thread covers 2 n x 4 k of one 32x32 hash tile
    const int b_tile = tid >> 7;              // 0..3
    const int t7 = tid & 127;
    const int b_np = t7 & 15;                 // n-pair
    const int b_kg = t7 >> 4;                 // 0..7 : 4-k group
    const int b_oct = b_kg >> 1;
    // swizzled B position: within-oct pos, XORed by (n_even & 8) halves (16B gran)
    const unsigned b_base = b_oct * BSLAB;
    const unsigned b_pos = (b_tile * 32 + 2 * b_np) * 8 + (b_kg & 1) * 4;
    const unsigned bswz = (b_np & 4) << 1;    // = (n_even & 8)

    // two STATIC register sets (no arrays -> no dynamic indexing -> no spill)
    uint4 paA0, paA1, paB0, paB1;
    unsigned pbA0, pbA1, pbA2, pbA3, pbB0, pbB1, pbB2, pbB3;

#define LOADT(P0, P1, Q0, Q1, Q2, Q3, kp_) do {                                \
        P0 = *(const uint4*)(aptr + (kp_) * 32);                               \
        P1 = *(const uint4*)(aptr + (size_t)128 * KDIM + (kp_) * 32);          \
        int st = Ss[(kp_) * 4 + b_tile];                                       \
        const __half* src = hh + st + b_kg * 128 + b_np * 2;                   \
        Q0 = *(const unsigned*)(src);                                          \
        Q1 = *(const unsigned*)(src + 32);                                     \
        Q2 = *(const unsigned*)(src + 64);                                     \
        Q3 = *(const unsigned*)(src + 96);                                     \
    } while (0)

#define STORET(P0, P1, Q0, Q1, Q2, Q3, buf_) do {                              \
        *(uint4*)&As[buf_][a_woff] = P0;                                       \
        *(uint4*)&As[buf_][(a_woff) + 128 * ASTRIDE] = P1;                     \
        unsigned lo0 = (Q0 & 0xffffu) | (Q1 << 16);                            \
        unsigned lo1 = (Q2 & 0xffffu) | (Q3 << 16);                            \
        unsigned hi0 = (Q0 >> 16) | (Q1 & 0xffff0000u);                        \
        unsigned hi1 = (Q2 >> 16) | (Q3 & 0xffff0000u);                        \
        uint2 e = {lo0, lo1}, o = {hi0, hi1};                                  \
        *(uint2*)&Bs[buf_][b_base + (b_pos ^ bswz)] = e;                       \
        *(uint2*)&Bs[buf_][b_base + ((b_pos + 8) ^ bswz)] = o;                 \
    } while (0)

    floatx4 acc[4][4];
#pragma unroll
    for (int r = 0; r < 4; r++)
#pragma unroll
        for (int c = 0; c < 4; c++)
            acc[r][c] = (floatx4){0.f, 0.f, 0.f, 0.f};

    const unsigned rswz = (unsigned)(l16 & 8);   // = (n & 8) for this lane's B cols

#define FRAGS_MFMA(buf_) do {                                                  \
        half8 af[4], bf[4];                                                    \
        _Pragma("unroll")                                                      \
        for (int r = 0; r < 4; r++)                                            \
            af[r] = *(const half8*)&As[buf_][(wm * 64 + r * 16 + l16) * ASTRIDE + quad * 8]; \
        _Pragma("unroll")                                                      \
        for (int c = 0; c < 4; c++)                                            \
            bf[c] = *(const half8*)&Bs[buf_][quad * BSLAB + ((unsigned)((wn * 64 + c * 16 + l16) * 8) ^ rswz)]; \
        _Pragma("unroll")                                                      \
        for (int r = 0; r < 4; r++)                                            \
            _Pragma("unroll")                                                  \
            for (int c = 0; c < 4; c++)                                        \
                acc[r][c] = __builtin_amdgcn_mfma_f32_16x16x32_f16(af[r], bf[c], acc[r][c], 0, 0, 0); \
    } while (0)

    __syncthreads();                  // Ss visible
    LOADT(paA0, paA1, pbA0, pbA1, pbA2, pbA3, 0);   // tile 0 -> set A
    LOADT(paB0, paB1, pbB0, pbB1, pbB2, pbB3, 1);   // tile 1 -> set B
    STORET(paA0, paA1, pbA0, pbA1, pbA2, pbA3, 0);  // waits set A only
    __syncthreads();

    for (int kp = 0; kp < KITER; kp += 2) {
        // even half-iter: compute tile kp from buf0; set A free
        if (kp + 2 < KITER) LOADT(paA0, paA1, pbA0, pbA1, pbA2, pbA3, kp + 2);
        FRAGS_MFMA(0);
        STORET(paB0, paB1, pbB0, pbB1, pbB2, pbB3, 1);   // tile kp+1 (loaded 1 iter ago)
        __syncthreads();

        // odd half-iter: compute tile kp+1 from buf1; set B free
        if (kp + 3 < KITER) LOADT(paB0, paB1, pbB0, pbB1, pbB2, pbB3, kp + 3);
        FRAGS_MFMA(1);
        if (kp + 2 < KITER)
            STORET(paA0, paA1, pbA0, pbA1, pbA2, pbA3, 0); // tile kp+2 (loaded 1 iter ago)
        __syncthreads();
    }

    // ---- epilogue: atomic accumulate (C/D layout col=lane&15, row=quad*4+reg) ----
#pragma unroll
    for (int c = 0; c < 4; c++) {
        int col = gn0 + wn * 64 + c * 16 + l16;
#pragma unroll
        for (int r = 0; r < 4; r++) {
            int row0 = gm0 + wm * 64 + r * 16 + quad * 4;
#pragma unroll
            for (int e = 0; e < 4; e++)
                atomicAdd(&out[(size_t)(row0 + e) * NDIM + col], acc[r][c][e]);
        }
    }
#undef LOADT
#undef STORET
#undef FRAGS_MFMA
}

extern "C" void kernel_launch(void* const* d_in, const int* in_sizes, int n_in,
                              void* d_out, int out_size, void* d_ws, size_t ws_size,
                              hipStream_t stream) {
    const float* x = (const float*)d_in[0];
    const float* hw = (const float*)d_in[1];
    const float* bias = (const float*)d_in[2];
    const int* rn = (const int*)d_in[3];
    float* out = (float*)d_out;

    char* ws = (char*)d_ws;
    __half* xh = (__half*)ws;                          // 8 MB : x as f16
    __half* hh = (__half*)(ws + (8u << 20));           // 8 MB : hashed_weight as f16
    int* starts = (int*)(ws + (16u << 20));            // 256 KB : tile start table

    hipLaunchKernelGGL(prep_kernel, dim3(12544), dim3(256), 0, stream,
                       x, hw, bias, rn, xh, hh, starts, out);
    hipLaunchKernelGGL(gemm_kernel, dim3(512), dim3(512), 0, stream, xh, hh, starts, out);
}

// Round 7
// 198.432 us; speedup vs baseline: 1.2770x; 1.0088x over previous
//
#include <hip/hip_runtime.h>
#include <hip/hip_fp16.h>

#define NDIM 8192
#define KDIM 8192
#define NT 256          // N / 32 hash tiles
#define MOD2 4193281    // HASH_SIZE - 32*32 + 1
#define PRIME 2038074743LL

#define BM 256
#define BN 128
#define BK 32
#define KITER 64        // (KDIM/4)/BK, split-K = 4
#define BSLAB 1032      // halves per k-octet slab (128*8 + 8 pad; phase-balanced)

typedef _Float16 half8 __attribute__((ext_vector_type(8)));
typedef float floatx4 __attribute__((ext_vector_type(4)));

// ---------------- fused prepass: cvt fp32->f16, out=bias, ROBE-Z starts ----------------
__global__ __launch_bounds__(256) void prep_kernel(const float* __restrict__ x,
                                                   const float* __restrict__ hw,
                                                   const float* __restrict__ bias,
                                                   const int* __restrict__ rn,
                                                   __half* __restrict__ xh,
                                                   __half* __restrict__ hh,
                                                   int* __restrict__ starts,
                                                   float* __restrict__ out) {
    int b = blockIdx.x;
    int tid = threadIdx.x;
    if (b < 8192) {                       // cvt: 2M threads x 4 floats
        int i = b * 256 + tid;
        const float4* s; __half2* d; int j;
        if (i < (1 << 20)) { s = (const float4*)x;  d = (__half2*)xh; j = i; }
        else               { s = (const float4*)hw; d = (__half2*)hh; j = i - (1 << 20); }
        float4 v = s[j];
        d[j * 2]     = __floats2half2_rn(v.x, v.y);
        d[j * 2 + 1] = __floats2half2_rn(v.z, v.w);
    } else if (b < 8192 + 4096) {         // init: out = bias (atomic targets)
        int i = (b - 8192) * 256 + tid;
        float4 bv = *(const float4*)(bias + ((i & 2047) << 2));
        ((float4*)out)[i] = bv;
    } else {                              // starts: 64K hash tile offsets
        int t = (b - 12288) * 256 + tid;
        bool is64 = (rn[1] == 0 && rn[3] == 0);   // int64 input: words 1,3 are hi-halves
        long long R1 = is64 ? rn[2] : rn[1];
        long long R2 = is64 ? rn[4] : rn[2];
        long long R3 = is64 ? rn[6] : rn[3];
        long long k_id = t >> 8, n_id = t & 255;
        long long v = (k_id * R3 + n_id * R2 + R1) % PRIME;
        starts[t] = (int)(v % MOD2);
    }
}

// async global->LDS, 16B per lane; LDS dest = wave-uniform base + lane*16 (HW)
__device__ __forceinline__ void gload16(const __half* g, __half* l) {
    __builtin_amdgcn_global_load_lds((const __attribute__((address_space(1))) void*)g,
                                     (__attribute__((address_space(3))) void*)l, 16, 0, 0);
}

// ---------------- main GEMM: split-K=4, 256x128 block, dist-2 B prefetch ----------------
// R6-proven structure (123.6us). Changes: A staged via global_load_lds width=16
// (linear LDS dest, XOR-swizzled per-lane global source, same XOR on read);
// A-pad dropped -> LDS 58.9->50.3KB -> 3 blocks/CU. B path identical to R6.
__global__ __launch_bounds__(512, 4) void gemm_kernel(
    const __half* __restrict__ xh, const __half* __restrict__ hh,
    const int* __restrict__ starts, float* __restrict__ out) {
    __shared__ __align__(16) __half As[2][BM * 32];        // [m][k] linear, swizzled chunks
    __shared__ __align__(16) __half Bs[2][4 * BSLAB];      // [k-octet][n][8] k-runs, swizzled
    __shared__ int Ss[KITER * 4];                          // per-block starts table

    const int tid = threadIdx.x;
    const int lane = tid & 63;
    const int wave = tid >> 6;       // 0..7
    const int wm = wave >> 1;        // 0..3 : 64-row strip
    const int wn = wave & 1;         // 0..1 : 64-col strip
    const int quad = lane >> 4;
    const int l16 = lane & 15;

    const int i = blockIdx.x;        // 512 blocks
    const int ks = i & 3;
    const int m_blk = (i >> 2) & 1;
    const int n_blk = i >> 3;        // 0..63
    const int gm0 = m_blk * BM;
    const int gn0 = n_blk * BN;
    const int kt0 = ks * KITER;
    const int n_id0 = n_blk * 4;     // 4 hash tiles per block

    if (tid < KITER * 4) {
        int kp = tid >> 2, tile = tid & 3;
        Ss[tid] = starts[(kt0 + kp) * NT + n_id0 + tile];
    }

    // ---- A staging via global_load_lds: wave t covers rows t*16..t*16+15 per instr ----
    // swizzle: LDS chunk-pos p of row holds global chunk p ^ ((row>>1)&3).
    // On write, (row>>1)&3 == (lane>>3)&3 (lane-constant); on read == (l16>>1)&3.
    const int a_t = wave * 2;                              // first of this wave's 2 instrs
    const int a_chunk = (lane & 3) ^ ((lane >> 3) & 3);    // swizzled global chunk
    const __half* a_g0 = xh + (size_t)(gm0 + a_t * 16 + (lane >> 2)) * KDIM
                         + kt0 * 32 + a_chunk * 8;
    const __half* a_g1 = a_g0 + (size_t)16 * KDIM;         // rows +16

#define STAGE_A(buf_, kp_) do {                                                \
        gload16(a_g0 + (kp_) * 32, &As[buf_][a_t * 512]);                      \
        gload16(a_g1 + (kp_) * 32, &As[buf_][a_t * 512 + 512]);                \
    } while (0)

    // ---- B staging (reg-staged pack, R6-verbatim) ----
    const int b_tile = tid >> 7;              // 0..3
    const int t7 = tid & 127;
    const int b_np = t7 & 15;                 // n-pair
    const int b_kg = t7 >> 4;                 // 0..7 : 4-k group
    const int b_oct = b_kg >> 1;
    const unsigned b_base = b_oct * BSLAB;
    const unsigned b_pos = (b_tile * 32 + 2 * b_np) * 8 + (b_kg & 1) * 4;
    const unsigned bswz = (b_np & 4) << 1;    // = (n_even & 8)

    unsigned pbA0, pbA1, pbA2, pbA3, pbB0, pbB1, pbB2, pbB3;

#define LOADT(Q0, Q1, Q2, Q3, kp_) do {                                        \
        int st = Ss[(kp_) * 4 + b_tile];                                       \
        const __half* src = hh + st + b_kg * 128 + b_np * 2;                   \
        Q0 = *(const unsigned*)(src);                                          \
        Q1 = *(const unsigned*)(src + 32);                                     \
        Q2 = *(const unsigned*)(src + 64);                                     \
        Q3 = *(const unsigned*)(src + 96);                                     \
    } while (0)

#define STORET(Q0, Q1, Q2, Q3, buf_) do {                                      \
        unsigned lo0 = (Q0 & 0xffffu) | (Q1 << 16);                            \
        unsigned lo1 = (Q2 & 0xffffu) | (Q3 << 16);                            \
        unsigned hi0 = (Q0 >> 16) | (Q1 & 0xffff0000u);                        \
        unsigned hi1 = (Q2 >> 16) | (Q3 & 0xffff0000u);                        \
        uint2 e = {lo0, lo1}, o = {hi0, hi1};                                  \
        *(uint2*)&Bs[buf_][b_base + (b_pos ^ bswz)] = e;                       \
        *(uint2*)&Bs[buf_][b_base + ((b_pos + 8) ^ bswz)] = o;                 \
    } while (0)

    floatx4 acc[4][4];
#pragma unroll
    for (int r = 0; r < 4; r++)
#pragma unroll
        for (int c = 0; c < 4; c++)
            acc[r][c] = (floatx4){0.f, 0.f, 0.f, 0.f};

    const unsigned rswz = (unsigned)(l16 & 8);        // B read swizzle (R6)
    const unsigned a_rswz = (unsigned)((l16 >> 1) & 3); // A read chunk swizzle

#define FRAGS_MFMA(buf_) do {                                                  \
        half8 af[4], bf[4];                                                    \
        _Pragma("unroll")                                                      \
        for (int r = 0; r < 4; r++)                                            \
            af[r] = *(const half8*)&As[buf_][(unsigned)(wm * 64 + r * 16 + l16) * 32 \
                                             + ((quad ^ a_rswz) * 8)];         \
        _Pragma("unroll")                                                      \
        for (int c = 0; c < 4; c++)                                            \
            bf[c] = *(const half8*)&Bs[buf_][quad * BSLAB + ((unsigned)((wn * 64 + c * 16 + l16) * 8) ^ rswz)]; \
        _Pragma("unroll")                                                      \
        for (int r = 0; r < 4; r++)                                            \
            _Pragma("unroll")                                                  \
            for (int c = 0; c < 4; c++)                                        \
                acc[r][c] = __builtin_amdgcn_mfma_f32_16x16x32_f16(af[r], bf[c], acc[r][c], 0, 0, 0); \
    } while (0)

    __syncthreads();                  // Ss visible
    STAGE_A(0, 0);                    // A tile 0 -> buf0 (async)
    LOADT(pbA0, pbA1, pbA2, pbA3, 0); // B tile 0 -> set A
    LOADT(pbB0, pbB1, pbB2, pbB3, 1); // B tile 1 -> set B
    STORET(pbA0, pbA1, pbA2, pbA3, 0);
    __syncthreads();                  // drains vmcnt -> A(0) ready

    for (int kp = 0; kp < KITER; kp += 2) {
        // even half-iter: compute tile kp from buf0; stage tile kp+1 A into buf1
        STAGE_A(1, kp + 1);
        if (kp + 2 < KITER) LOADT(pbA0, pbA1, pbA2, pbA3, kp + 2);
        FRAGS_MFMA(0);
        STORET(pbB0, pbB1, pbB2, pbB3, 1);    // B tile kp+1 (loaded 1 iter ago)
        __syncthreads();

        // odd half-iter: compute tile kp+1 from buf1; stage tile kp+2 A into buf0
        if (kp + 2 < KITER) STAGE_A(0, kp + 2);
        if (kp + 3 < KITER) LOADT(pbB0, pbB1, pbB2, pbB3, kp + 3);
        FRAGS_MFMA(1);
        if (kp + 2 < KITER)
            STORET(pbA0, pbA1, pbA2, pbA3, 0); // B tile kp+2 (loaded 1 iter ago)
        __syncthreads();
    }

    // ---- epilogue: atomic accumulate (C/D layout col=lane&15, row=quad*4+reg) ----
#pragma unroll
    for (int c = 0; c < 4; c++) {
        int col = gn0 + wn * 64 + c * 16 + l16;
#pragma unroll
        for (int r = 0; r < 4; r++) {
            int row0 = gm0 + wm * 64 + r * 16 + quad * 4;
#pragma unroll
            for (int e = 0; e < 4; e++)
                atomicAdd(&out[(size_t)(row0 + e) * NDIM + col], acc[r][c][e]);
        }
    }
#undef LOADT
#undef STORET
#undef FRAGS_MFMA
#undef STAGE_A
}

extern "C" void kernel_launch(void* const* d_in, const int* in_sizes, int n_in,
                              void* d_out, int out_size, void* d_ws, size_t ws_size,
                              hipStream_t stream) {
    const float* x = (const float*)d_in[0];
    const float* hw = (const float*)d_in[1];
    const float* bias = (const float*)d_in[2];
    const int* rn = (const int*)d_in[3];
    float* out = (float*)d_out;

    char* ws = (char*)d_ws;
    __half* xh = (__half*)ws;                          // 8 MB : x as f16
    __half* hh = (__half*)(ws + (8u << 20));           // 8 MB : hashed_weight as f16
    int* starts = (int*)(ws + (16u << 20));            // 256 KB : tile start table

    hipLaunchKernelGGL(prep_kernel, dim3(12544), dim3(256), 0, stream,
                       x, hw, bias, rn, xh, hh, starts, out);
    hipLaunchKernelGGL(gemm_kernel, dim3(512), dim3(512), 0, stream, xh, hh, starts, out);
}